// Round 8
// baseline (326.765 us; speedup 1.0000x reference)
//
#include <hip/hip_runtime.h>
#include <math.h>

#define TT 4096
#define DM 1024
#define BB 4
#define BT (BB * TT)
#define SENTINEL 0x7fffffff
#define NBLK 512    // 2 blocks/CU: LDS 33KB*2 <= 160KB, co-residency guaranteed
#define NTHR 256

// ws layout (bytes):
//   Q     : float[BT*2]  @ 0        (131072)
//   K     : float[BT*2]  @ 131072   (131072)
//   idx   : int[BT]      @ 262144   (65536)
//   rep   : int[BT]      @ 327680   (65536)   (claim flag)
//   list  : int[BT]      @ 393216   (65536)
//   vpos  : int[BT]      @ 458752   (65536)
//   cnt   : int          @ 524288   (4)
//   barrier region       @ 524416   (8448)   <- memset 0 each call
//     gcnt[64] : one int per 128-B line (64*128 = 8192)
//     root     : @ +8192 (own line)
//     gen      : @ +8320 (own line; written once per barrier, polled)
//   vrows : float[...]   @ 1048576

__device__ __forceinline__ float dot4(const float4 a, const float4 b) {
    return a.x * b.x + a.y * b.y + a.z * b.z + a.w * b.w;
}

// Two-level grid barrier. Arrival RMWs and the polled generation word live on
// DIFFERENT cachelines (R6 failure: pollers thrashed the arrival line).
__device__ __forceinline__ void grid_barrier(int* gcnt, int* root, int* gen, int it) {
    __syncthreads();
    if (threadIdx.x == 0) {
        __threadfence();                                  // publish this block's writes
        const int gid = blockIdx.x >> 3;                  // 64 groups of 8 blocks
        if (atomicAdd(&gcnt[gid * 32], 1) == it * 8 + 7) {        // last in group
            if (atomicAdd(root, 1) == it * 64 + 63) {             // last group
                __threadfence();
                __hip_atomic_store(gen, it + 1, __ATOMIC_RELEASE, __HIP_MEMORY_SCOPE_AGENT);
            }
        }
        while (__hip_atomic_load(gen, __ATOMIC_ACQUIRE, __HIP_MEMORY_SCOPE_AGENT) <= it)
            __builtin_amdgcn_s_sleep(16);
        __threadfence();                                  // acquire other blocks' writes
    }
    __syncthreads();
}

__global__ __launch_bounds__(NTHR, 2) void fused_kernel(const float* __restrict__ x,
                                                        const float* __restrict__ wq,
                                                        const float* __restrict__ wk,
                                                        const float* __restrict__ wv,
                                                        float* __restrict__ Q,
                                                        float* __restrict__ K,
                                                        int* __restrict__ idx,
                                                        int* __restrict__ rep,
                                                        int* __restrict__ list,
                                                        int* __restrict__ vpos,
                                                        int* __restrict__ cnt,
                                                        int* __restrict__ gcnt,
                                                        int* __restrict__ root,
                                                        int* __restrict__ gen,
                                                        float* __restrict__ vrows,
                                                        float* __restrict__ out) {
    __shared__ float4 ks4[TT / 2];     // 32 KB (phase 2)
    __shared__ int sli[32];            // phase 4 stage

    const int tid = threadIdx.x;
    const int wave = tid >> 6, lane = tid & 63;
    const int bid = blockIdx.x;

    // ================= Phase 1: Q,K projection (+rep/cnt init) =================
    {
        if (tid < 32) rep[bid * 32 + tid] = SENTINEL;
        if (bid == 0 && tid == 32) cnt[0] = 0;

        float4 wq0[4], wq1[4], wk0[4], wk1[4];
        #pragma unroll
        for (int j = 0; j < 4; ++j) {
            wq0[j] = ((const float4*)(wq))[j * 64 + lane];
            wq1[j] = ((const float4*)(wq + DM))[j * 64 + lane];
            wk0[j] = ((const float4*)(wk))[j * 64 + lane];
            wk1[j] = ((const float4*)(wk + DM))[j * 64 + lane];
        }
        const int row0 = bid * 32;
        #pragma unroll
        for (int i = 0; i < 8; ++i) {
            const int row = row0 + i * 4 + wave;
            const float4* xr = (const float4*)(x + (size_t)row * DM);
            float s0 = 0.f, s1 = 0.f, s2 = 0.f, s3 = 0.f;
            #pragma unroll
            for (int j = 0; j < 4; ++j) {
                const float4 xv = xr[j * 64 + lane];
                s0 += dot4(xv, wq0[j]);
                s1 += dot4(xv, wq1[j]);
                s2 += dot4(xv, wk0[j]);
                s3 += dot4(xv, wk1[j]);
            }
            #pragma unroll
            for (int off = 32; off > 0; off >>= 1) {
                s0 += __shfl_down(s0, off);
                s1 += __shfl_down(s1, off);
                s2 += __shfl_down(s2, off);
                s3 += __shfl_down(s3, off);
            }
            if (lane == 0) {
                ((float2*)Q)[row] = make_float2(s0, s1);
                ((float2*)K)[row] = make_float2(s2, s3);
            }
        }
    }
    grid_barrier(gcnt, root, gen, 0);

    // ================= Phase 2: causal argmax (claim + compact) =================
    {
        const int b  = bid >> 7;       // 128 blocks per batch
        const int cc = bid & 127;      // t ≡ cc (mod 128)
        const float4* kb4 = (const float4*)(K + (size_t)b * TT * 2);
        for (int i = tid; i < TT / 2; i += NTHR) ks4[i] = kb4[i];
        __syncthreads();

        for (int m = wave; m < 32; m += 4) {
            const int t = cc + (m << 7);
            const float2 q = ((const float2*)Q)[b * TT + t];

            float best = -INFINITY;
            int bi = 0x7fffffff;
            int p = lane;
            // pair p -> points 2p, 2p+1; in-lane ascending s + strict '>'
            while (2 * (p + 64) + 1 <= t) {
                const float4 a = ks4[p];
                const float4 d = ks4[p + 64];
                const float c0 = q.x * a.x + q.y * a.y;
                const float c1 = q.x * a.z + q.y * a.w;
                const float c2 = q.x * d.x + q.y * d.y;
                const float c3 = q.x * d.z + q.y * d.w;
                if (c0 > best) { best = c0; bi = 2 * p; }
                if (c1 > best) { best = c1; bi = 2 * p + 1; }
                if (c2 > best) { best = c2; bi = 2 * (p + 64); }
                if (c3 > best) { best = c3; bi = 2 * (p + 64) + 1; }
                p += 128;
            }
            while (2 * p <= t) {
                const float4 a = ks4[p];
                const float c0 = q.x * a.x + q.y * a.y;
                if (c0 > best) { best = c0; bi = 2 * p; }
                if (2 * p + 1 <= t) {
                    const float c1 = q.x * a.z + q.y * a.w;
                    if (c1 > best) { best = c1; bi = 2 * p + 1; }
                }
                p += 64;
            }
            // cross-lane argmax, first-occurrence tie-break
            #pragma unroll
            for (int off = 32; off > 0; off >>= 1) {
                const float ov = __shfl_down(best, off);
                const int   oi = __shfl_down(bi, off);
                if (ov > best || (ov == best && oi < bi)) { best = ov; bi = oi; }
            }
            if (lane == 0) {
                idx[b * TT + t] = bi;
                const int bs = b * TT + bi;
                if (atomicMin(&rep[bs], t) == SENTINEL) {   // first claimant
                    const int pp = atomicAdd(cnt, 1);
                    list[pp] = bs;
                    vpos[bs] = pp;
                }
            }
        }
    }
    grid_barrier(gcnt, root, gen, 1);

    // ================= Phase 3: V-rows into compact vrows =================
    {
        const int slice = bid >> 3;            // 64 slices of 16 cols
        const int usub  = bid & 7;             // 8-way split over unique rows
        const int e0 = slice * 16 + wave * 4;

        float4 w[4][4];
        #pragma unroll
        for (int r = 0; r < 4; ++r) {
            const float4* wr = (const float4*)(wv + (size_t)(e0 + r) * DM);
            #pragma unroll
            for (int j = 0; j < 4; ++j) w[r][j] = wr[j * 64 + lane];
        }

        const int n = cnt[0];
        if (usub < n) {
            // software-pipelined: prefetch next x-row while reducing current
            float4 xv[4];
            {
                const float4* xr = (const float4*)(x + (size_t)list[usub] * DM);
                #pragma unroll
                for (int j = 0; j < 4; ++j) xv[j] = xr[j * 64 + lane];
            }
            for (int li = usub; li < n; li += 8) {
                float4 xn[4];
                if (li + 8 < n) {
                    const float4* xr = (const float4*)(x + (size_t)list[li + 8] * DM);
                    #pragma unroll
                    for (int j = 0; j < 4; ++j) xn[j] = xr[j * 64 + lane];
                }
                float s0 = 0.f, s1 = 0.f, s2 = 0.f, s3 = 0.f;
                #pragma unroll
                for (int j = 0; j < 4; ++j) {
                    s0 += dot4(w[0][j], xv[j]);
                    s1 += dot4(w[1][j], xv[j]);
                    s2 += dot4(w[2][j], xv[j]);
                    s3 += dot4(w[3][j], xv[j]);
                }
                #pragma unroll
                for (int off = 32; off > 0; off >>= 1) {
                    s0 += __shfl_down(s0, off);
                    s1 += __shfl_down(s1, off);
                    s2 += __shfl_down(s2, off);
                    s3 += __shfl_down(s3, off);
                }
                if (lane == 0)
                    *(float4*)(vrows + (size_t)li * DM + e0) = make_float4(s0, s1, s2, s3);
                #pragma unroll
                for (int j = 0; j < 4; ++j) xv[j] = xn[j];
            }
        }
    }
    grid_barrier(gcnt, root, gen, 2);

    // ================= Phase 4: write-only gather from L2-resident vrows =================
    {
        const int row0 = bid * 32;
        if (tid < 32) {
            const int bt = row0 + tid;
            const int b = bt >> 12;
            sli[tid] = vpos[b * TT + idx[bt]];
        }
        __syncthreads();
        #pragma unroll 4
        for (int i = 0; i < 32; ++i) {
            const float4* src = (const float4*)(vrows + (size_t)sli[i] * DM);
            float4* dst = (float4*)(out + (size_t)(row0 + i) * DM);
            dst[tid] = src[tid];
        }
    }
}

extern "C" void kernel_launch(void* const* d_in, const int* in_sizes, int n_in,
                              void* d_out, int out_size, void* d_ws, size_t ws_size,
                              hipStream_t stream) {
    const float* x  = (const float*)d_in[0];
    const float* wq = (const float*)d_in[1];
    const float* wk = (const float*)d_in[2];
    const float* wv = (const float*)d_in[3];
    float* out = (float*)d_out;

    char* ws = (char*)d_ws;
    float* Q     = (float*)(ws);
    float* K     = (float*)(ws + 131072);
    int*   idx   = (int*)  (ws + 262144);
    int*   rep   = (int*)  (ws + 327680);
    int*   list  = (int*)  (ws + 393216);
    int*   vpos  = (int*)  (ws + 458752);
    int*   cnt   = (int*)  (ws + 524288);
    int*   gcnt  = (int*)  (ws + 524416);            // 64 x 128-B lines
    int*   root  = (int*)  (ws + 524416 + 8192);     // own line
    int*   gen   = (int*)  (ws + 524416 + 8320);     // own line
    float* vrows = (float*)(ws + 1048576);

    hipMemsetAsync(ws + 524416, 0, 8448, stream);    // zero barrier region
    fused_kernel<<<NBLK, NTHR, 0, stream>>>(x, wq, wk, wv, Q, K, idx, rep, list,
                                            vpos, cnt, gcnt, root, gen, vrows, out);
}

// Round 9
// 217.527 us; speedup vs baseline: 1.5022x; 1.5022x over previous
//
#include <hip/hip_runtime.h>
#include <math.h>

#define TT 4096
#define DM 1024
#define BB 4
#define BT (BB * TT)
#define SENTINEL 0x7fffffff

// ws layout (bytes):
//   Q     : float[BT*2]  @ 0        (131072)
//   K     : float[BT*2]  @ 131072   (131072)  (interleaved k0,k1 pairs)
//   idx   : int[BT]      @ 262144   (65536)
//   rep   : int[BT]      @ 327680   (65536)   (claim flags / earliest t)
//   list  : int[BT]      @ 393216   (65536)   (compact unique source rows)
//   vpos  : int[BT]      @ 458752   (65536)   (bs -> position in list/vrows)
//   cnt   : int          @ 524288   (4)
//   vrows : float[BT*DM] @ 1048576  (compact V rows)

__device__ __forceinline__ float dot4(const float4 a, const float4 b) {
    return a.x * b.x + a.y * b.y + a.z * b.z + a.w * b.w;
}

// ---------- Kernel 1: Q,K projection. 4 rows/block (4096 blocks), weights in regs.
//            Also initializes rep[] and cnt. ----------
__global__ __launch_bounds__(256) void qk_kernel(const float* __restrict__ x,
                                                 const float* __restrict__ wq,
                                                 const float* __restrict__ wk,
                                                 float* __restrict__ Q,
                                                 float* __restrict__ K,
                                                 int* __restrict__ rep,
                                                 int* __restrict__ cnt) {
    const int tid = threadIdx.x;
    const int wave = tid >> 6, lane = tid & 63;
    const int row0 = blockIdx.x * 4;

    if (tid < 4) rep[row0 + tid] = SENTINEL;
    if (row0 == 0 && tid == 4) cnt[0] = 0;

    float4 wq0[4], wq1[4], wk0[4], wk1[4];
    #pragma unroll
    for (int j = 0; j < 4; ++j) {
        wq0[j] = ((const float4*)(wq))[j * 64 + lane];
        wq1[j] = ((const float4*)(wq + DM))[j * 64 + lane];
        wk0[j] = ((const float4*)(wk))[j * 64 + lane];
        wk1[j] = ((const float4*)(wk + DM))[j * 64 + lane];
    }
    const int row = row0 + wave;
    const float4* xr = (const float4*)(x + (size_t)row * DM);
    float4 xv[4];
    #pragma unroll
    for (int j = 0; j < 4; ++j) xv[j] = xr[j * 64 + lane];

    float s0 = 0.f, s1 = 0.f, s2 = 0.f, s3 = 0.f;
    #pragma unroll
    for (int j = 0; j < 4; ++j) {
        s0 += dot4(xv[j], wq0[j]);
        s1 += dot4(xv[j], wq1[j]);
        s2 += dot4(xv[j], wk0[j]);
        s3 += dot4(xv[j], wk1[j]);
    }
    #pragma unroll
    for (int off = 32; off > 0; off >>= 1) {
        s0 += __shfl_down(s0, off);
        s1 += __shfl_down(s1, off);
        s2 += __shfl_down(s2, off);
        s3 += __shfl_down(s3, off);
    }
    if (lane == 0) {
        ((float2*)Q)[row] = make_float2(s0, s1);
        ((float2*)K)[row] = make_float2(s2, s3);
    }
}

// ---------- Kernel 2: causal argmax. Wave-per-t, float4 LDS fill + scan, claim+compact.
//            Block->tg bit-swap swizzle spreads heavy tails across dispatch order. ----------
__global__ __launch_bounds__(256) void argmax_kernel(const float* __restrict__ Q,
                                                     const float* __restrict__ K,
                                                     int* __restrict__ idx,
                                                     int* __restrict__ rep,
                                                     int* __restrict__ list,
                                                     int* __restrict__ vpos,
                                                     int* __restrict__ cnt) {
    __shared__ float4 ks4[TT / 2];   // 32 KB; pair p -> points 2p, 2p+1
    const int b   = blockIdx.x >> 10;
    const int tgr = blockIdx.x & 1023;
    const int tg  = ((tgr & 31) << 5) | (tgr >> 5);   // load-balance swizzle
    const int tid = threadIdx.x;
    const int nfill4 = tg * 2 + 2;       // float4 count covering points 0..t_max

    const float4* kb4 = (const float4*)(K + (size_t)b * TT * 2);
    for (int i = tid; i < nfill4; i += 256) ks4[i] = kb4[i];
    __syncthreads();

    const int wave = tid >> 6, lane = tid & 63;
    const int t = tg * 4 + wave;
    const float2 q = ((const float2*)Q)[b * TT + t];

    float best = -INFINITY;
    int bi = 0x7fffffff;
    int p = lane;
    // main: both pairs fully in range; in-lane ascending s order + strict '>'
    while (2 * (p + 64) + 1 <= t) {
        const float4 a = ks4[p];
        const float4 c = ks4[p + 64];
        const float c0 = q.x * a.x + q.y * a.y;
        const float c1 = q.x * a.z + q.y * a.w;
        const float c2 = q.x * c.x + q.y * c.y;
        const float c3 = q.x * c.z + q.y * c.w;
        if (c0 > best) { best = c0; bi = 2 * p; }
        if (c1 > best) { best = c1; bi = 2 * p + 1; }
        if (c2 > best) { best = c2; bi = 2 * (p + 64); }
        if (c3 > best) { best = c3; bi = 2 * (p + 64) + 1; }
        p += 128;
    }
    while (2 * p <= t) {
        const float4 a = ks4[p];
        const float c0 = q.x * a.x + q.y * a.y;
        if (c0 > best) { best = c0; bi = 2 * p; }
        if (2 * p + 1 <= t) {
            const float c1 = q.x * a.z + q.y * a.w;
            if (c1 > best) { best = c1; bi = 2 * p + 1; }
        }
        p += 64;
    }
    // cross-lane argmax, first-occurrence tie-break (smaller index wins on equal)
    #pragma unroll
    for (int off = 32; off > 0; off >>= 1) {
        const float ov = __shfl_down(best, off);
        const int   oi = __shfl_down(bi, off);
        if (ov > best || (ov == best && oi < bi)) { best = ov; bi = oi; }
    }
    if (lane == 0) {
        idx[b * TT + t] = bi;
        const int bs = b * TT + bi;
        if (atomicMin(&rep[bs], t) == SENTINEL) {   // first claimant appends
            const int pp = atomicAdd(cnt, 1);
            list[pp] = bs;
            vpos[bs] = pp;
        }
    }
}

// ---------- Kernel 3: V-rows into compact vrows. 64 slices x 16 usub;
//            early-exit BEFORE the 64 KB W_V slice load. ----------
__global__ __launch_bounds__(256) void vrow_kernel(const float* __restrict__ x,
                                                   const float* __restrict__ wv,
                                                   const int* __restrict__ list,
                                                   const int* __restrict__ cnt,
                                                   float* __restrict__ vrows) {
    const int tid = threadIdx.x, wave = tid >> 6, lane = tid & 63;
    const int slice = blockIdx.x >> 4;     // [0,64)
    const int usub  = blockIdx.x & 15;
    const int n = cnt[0];
    if (usub >= n) return;                 // idle block: exit before W_V load

    const int e0 = slice * 16 + wave * 4;
    float4 w[4][4];
    #pragma unroll
    for (int r = 0; r < 4; ++r) {
        const float4* wr = (const float4*)(wv + (size_t)(e0 + r) * DM);
        #pragma unroll
        for (int j = 0; j < 4; ++j) w[r][j] = wr[j * 64 + lane];
    }

    for (int li = usub; li < n; li += 16) {
        const int bs = list[li];
        const float4* xr = (const float4*)(x + (size_t)bs * DM);
        float4 xv[4];
        #pragma unroll
        for (int j = 0; j < 4; ++j) xv[j] = xr[j * 64 + lane];

        float s0 = 0.f, s1 = 0.f, s2 = 0.f, s3 = 0.f;
        #pragma unroll
        for (int j = 0; j < 4; ++j) {
            s0 += dot4(w[0][j], xv[j]);
            s1 += dot4(w[1][j], xv[j]);
            s2 += dot4(w[2][j], xv[j]);
            s3 += dot4(w[3][j], xv[j]);
        }
        #pragma unroll
        for (int off = 32; off > 0; off >>= 1) {
            s0 += __shfl_down(s0, off);
            s1 += __shfl_down(s1, off);
            s2 += __shfl_down(s2, off);
            s3 += __shfl_down(s3, off);
        }
        if (lane == 0)
            *(float4*)(vrows + (size_t)li * DM + e0) = make_float4(s0, s1, s2, s3);
    }
}

// ---------- Kernel 4: write-only gather. 4 rows/block (4096 blocks); all 4 source
//            loads issued before any store (8 independent mem ops in flight). ----------
__global__ __launch_bounds__(256) void gather_kernel(const int* __restrict__ idx,
                                                     const int* __restrict__ vpos,
                                                     const float* __restrict__ vrows,
                                                     float* __restrict__ out) {
    __shared__ int sli[4];
    const int tid = threadIdx.x;
    const int row0 = blockIdx.x * 4;
    if (tid < 4) {
        const int bt = row0 + tid;
        const int b = bt >> 12;
        sli[tid] = vpos[b * TT + idx[bt]];
    }
    __syncthreads();
    const float4 v0 = ((const float4*)(vrows + (size_t)sli[0] * DM))[tid];
    const float4 v1 = ((const float4*)(vrows + (size_t)sli[1] * DM))[tid];
    const float4 v2 = ((const float4*)(vrows + (size_t)sli[2] * DM))[tid];
    const float4 v3 = ((const float4*)(vrows + (size_t)sli[3] * DM))[tid];
    ((float4*)(out + (size_t)(row0 + 0) * DM))[tid] = v0;
    ((float4*)(out + (size_t)(row0 + 1) * DM))[tid] = v1;
    ((float4*)(out + (size_t)(row0 + 2) * DM))[tid] = v2;
    ((float4*)(out + (size_t)(row0 + 3) * DM))[tid] = v3;
}

extern "C" void kernel_launch(void* const* d_in, const int* in_sizes, int n_in,
                              void* d_out, int out_size, void* d_ws, size_t ws_size,
                              hipStream_t stream) {
    const float* x  = (const float*)d_in[0];
    const float* wq = (const float*)d_in[1];
    const float* wk = (const float*)d_in[2];
    const float* wv = (const float*)d_in[3];
    float* out = (float*)d_out;

    char* ws = (char*)d_ws;
    float* Q     = (float*)(ws);
    float* K     = (float*)(ws + 131072);
    int*   idx   = (int*)  (ws + 262144);
    int*   rep   = (int*)  (ws + 327680);
    int*   list  = (int*)  (ws + 393216);
    int*   vpos  = (int*)  (ws + 458752);
    int*   cnt   = (int*)  (ws + 524288);
    float* vrows = (float*)(ws + 1048576);

    qk_kernel<<<BT / 4, 256, 0, stream>>>(x, wq, wk, Q, K, rep, cnt);
    argmax_kernel<<<4096, 256, 0, stream>>>(Q, K, idx, rep, list, vpos, cnt);
    vrow_kernel<<<1024, 256, 0, stream>>>(x, wv, list, cnt, vrows);
    gather_kernel<<<BT / 4, 256, 0, stream>>>(idx, vpos, vrows, out);
}